// Round 6
// baseline (766.685 us; speedup 1.0000x reference)
//
#include <hip/hip_runtime.h>

// GRU, fp16 MFMA + fp32 accum, T=512 B=1024 I=H=64.
// Round 6 = Round 5 with the cvt_pkrtz return-type compile fix.
// ONE WAVE PER BLOCK (64 blocks x 64 threads), no barriers, no LDS.
// R3/R4 data: 4-wave version spends ~1000+ cyc/step in ds_write->lgkmcnt->
// s_barrier->ds_read cross-wave h exchange. Here each wave owns all 16 batch
// rows x 64 units, gates computed TRANSPOSED (D[unit][batch]): weights are
// the A-operands (48 frags, 192 VGPR, loaded once; 1 wave/SIMD -> 512-VGPR
// budget), x/h are shared B-operands. h_new emerges in C-layout (batch on
// lane&15) and re-enters as B-frag (batch on lane&15): the unit-bit shuffle
// crosses only the 4 lane-groups => 16x ds_bpermute + 8 cndmask on packed
// fp16 pairs, same-wave, register-only. Per-step serial path ~850 cyc vs
// R3's 1970.
// C-layout (verified): col=lane&15, row=4*(lane>>4)+reg. A/B k-map bijection
// cancels between A and B operands (same mapping both sides).

typedef _Float16 half8  __attribute__((ext_vector_type(8)));
typedef __fp16   fp16x2 __attribute__((ext_vector_type(2)));
typedef float    f32x4  __attribute__((ext_vector_type(4)));
typedef int      i32x4  __attribute__((ext_vector_type(4)));

#define T_STEPS 512
#define BATCH   1024

struct XBuf { float4 a0, a1, b0, b1; };

__device__ __forceinline__ half8 cvt8(const float4& a, const float4& b) {
    half8 h;
    h[0] = (_Float16)a.x; h[1] = (_Float16)a.y; h[2] = (_Float16)a.z; h[3] = (_Float16)a.w;
    h[4] = (_Float16)b.x; h[5] = (_Float16)b.y; h[6] = (_Float16)b.z; h[7] = (_Float16)b.w;
    return h;
}

__device__ __forceinline__ half8 loadw8(const float* p) {
    const float4* q = (const float4*)p;
    return cvt8(q[0], q[1]);
}

__device__ __forceinline__ int packrtz(float x, float y) {
    fp16x2 p = __builtin_amdgcn_cvt_pkrtz(x, y);
    return __builtin_bit_cast(int, p);
}

#define MFMA16(A, B, C) __builtin_amdgcn_mfma_f32_16x16x32_f16((A), (B), (C), 0, 0, 0)

__global__ __launch_bounds__(64, 1)
void gru_1wave_kernel(const float* __restrict__ X,     // [T,B,64]
                      const float* __restrict__ W_ih,  // [192,64]
                      const float* __restrict__ W_hh,  // [192,64]
                      const float* __restrict__ b_ih,  // [192]
                      const float* __restrict__ b_hh,  // [192]
                      float* __restrict__ out)         // [T*B*64] ++ [B*64]
{
    const int l     = threadIdx.x;     // single wave
    const int b     = l & 15;          // batch row within tile (C column)
    const int g4    = l >> 4;          // lane group
    const int brow0 = blockIdx.x * 16;
    const bool hiHalf = (l >= 32);

    // bpermute lane indices (bytes): src_lane = b + 16*src_g4,
    // src_g4 = 2*(g4&1) + c, c = jp>>1.
    const int idx0 = (b + 16 * ((g4 & 1) << 1)) << 2;  // c = 0
    const int idx1 = idx0 + 64;                        // c = 1

    // ---- Weight A-fragments (rows = units), fp16, loaded once ----
    // Wxx[g][ut][kk][lane e] = W[g*64 + 16*ut + b][32*kk + 8*g4 + e]
    half8 Wih[3][4][2], Whh[3][4][2];
    #pragma unroll
    for (int g = 0; g < 3; ++g)
        #pragma unroll
        for (int ut = 0; ut < 4; ++ut)
            #pragma unroll
            for (int kk = 0; kk < 2; ++kk) {
                const int row = g * 64 + 16 * ut + b;
                Wih[g][ut][kk] = loadw8(W_ih + row * 64 + 32 * kk + 8 * g4);
                Whh[g][ut][kk] = loadw8(W_hh + row * 64 + 32 * kk + 8 * g4);
            }

    // ---- Biases in C-layout: unit = 16*ut + 4*g4 + i ----
    f32x4 bR[4], bZ[4], bNX[4], bNH[4];
    #pragma unroll
    for (int ut = 0; ut < 4; ++ut) {
        const int o = 16 * ut + 4 * g4;
        const float4 i0 = *(const float4*)(b_ih + o);
        const float4 h0 = *(const float4*)(b_hh + o);
        const float4 i1 = *(const float4*)(b_ih + 64 + o);
        const float4 h1 = *(const float4*)(b_hh + 64 + o);
        const float4 i2 = *(const float4*)(b_ih + 128 + o);
        const float4 h2 = *(const float4*)(b_hh + 128 + o);
        bR[ut][0] = i0.x + h0.x; bR[ut][1] = i0.y + h0.y;
        bR[ut][2] = i0.z + h0.z; bR[ut][3] = i0.w + h0.w;
        bZ[ut][0] = i1.x + h1.x; bZ[ut][1] = i1.y + h1.y;
        bZ[ut][2] = i1.z + h1.z; bZ[ut][3] = i1.w + h1.w;
        bNX[ut][0] = i2.x; bNX[ut][1] = i2.y; bNX[ut][2] = i2.z; bNX[ut][3] = i2.w;
        bNH[ut][0] = h2.x; bNH[ut][1] = h2.y; bNH[ut][2] = h2.z; bNH[ut][3] = h2.w;
    }

    // ---- state ----
    f32x4 hp[4] = {{0.f,0.f,0.f,0.f},{0.f,0.f,0.f,0.f},
                   {0.f,0.f,0.f,0.f},{0.f,0.f,0.f,0.f}};   // h, C-layout
    int hh[4][2] = {{0,0},{0,0},{0,0},{0,0}};              // packed fp16 pairs

#define ISSUE_X(XB, T) do {                                                   \
        const float* px_ = X + ((T) * BATCH + brow0 + b) * 64 + 8 * g4;       \
        (XB).a0 = ((const float4*)px_)[0];                                    \
        (XB).a1 = ((const float4*)px_)[1];                                    \
        (XB).b0 = ((const float4*)(px_ + 32))[0];                             \
        (XB).b1 = ((const float4*)(px_ + 32))[1];                             \
    } while (0)

    XBuf xb0, xb1;
    ISSUE_X(xb0, 0);
    ISSUE_X(xb1, 1);

    // STEP(T, XA): XA holds x(T); refills XA <- x(T+2).
#define STEP(T, XA) do {                                                      \
        /* h B-frags from packed h via same-wave bpermute (reg-only dep) */   \
        i32x4 f0v, f1v;                                                       \
        _Pragma("unroll")                                                     \
        for (int jp = 0; jp < 4; ++jp) {                                      \
            const int idx_ = (jp < 2) ? idx0 : idx1;                          \
            const int lo0 = __builtin_amdgcn_ds_bpermute(idx_, hh[0][jp & 1]);\
            const int hi0 = __builtin_amdgcn_ds_bpermute(idx_, hh[1][jp & 1]);\
            const int lo1 = __builtin_amdgcn_ds_bpermute(idx_, hh[2][jp & 1]);\
            const int hi1 = __builtin_amdgcn_ds_bpermute(idx_, hh[3][jp & 1]);\
            f0v[jp] = hiHalf ? hi0 : lo0;                                     \
            f1v[jp] = hiHalf ? hi1 : lo1;                                     \
        }                                                                     \
        const half8 Fh0 = __builtin_bit_cast(half8, f0v);                     \
        const half8 Fh1 = __builtin_bit_cast(half8, f1v);                     \
        /* x B-frags (loaded 2 steps ago) + issue prefetch */                 \
        const half8 xf0 = cvt8((XA).a0, (XA).a1);                             \
        const half8 xf1 = cvt8((XA).b0, (XA).b1);                             \
        { int tn_ = (T) + 2; if (tn_ > T_STEPS - 1) tn_ = T_STEPS - 1;        \
          ISSUE_X(XA, tn_); }                                                 \
        /* 48 MFMAs: x-side first (hides bpermute latency), then h-side */    \
        f32x4 aR[4], aZ[4], aNX[4], aNH[4];                                   \
        _Pragma("unroll")                                                     \
        for (int ut = 0; ut < 4; ++ut) {                                      \
            aR[ut]  = MFMA16(Wih[0][ut][0], xf0, bR[ut]);                     \
            aR[ut]  = MFMA16(Wih[0][ut][1], xf1, aR[ut]);                     \
            aZ[ut]  = MFMA16(Wih[1][ut][0], xf0, bZ[ut]);                     \
            aZ[ut]  = MFMA16(Wih[1][ut][1], xf1, aZ[ut]);                     \
            aNX[ut] = MFMA16(Wih[2][ut][0], xf0, bNX[ut]);                    \
            aNX[ut] = MFMA16(Wih[2][ut][1], xf1, aNX[ut]);                    \
        }                                                                     \
        _Pragma("unroll")                                                     \
        for (int ut = 0; ut < 4; ++ut) {                                      \
            aR[ut]  = MFMA16(Whh[0][ut][0], Fh0, aR[ut]);                     \
            aR[ut]  = MFMA16(Whh[0][ut][1], Fh1, aR[ut]);                     \
            aZ[ut]  = MFMA16(Whh[1][ut][0], Fh0, aZ[ut]);                     \
            aZ[ut]  = MFMA16(Whh[1][ut][1], Fh1, aZ[ut]);                     \
            aNH[ut] = MFMA16(Whh[2][ut][0], Fh0, bNH[ut]);                    \
            aNH[ut] = MFMA16(Whh[2][ut][1], Fh1, aNH[ut]);                    \
        }                                                                     \
        /* combine (per-lane, C-layout), pack h, store */                     \
        _Pragma("unroll")                                                     \
        for (int ut = 0; ut < 4; ++ut) {                                      \
            f32x4 hn4;                                                        \
            _Pragma("unroll")                                                 \
            for (int i = 0; i < 4; ++i) {                                     \
                const float rv = __builtin_amdgcn_rcpf(1.f + __expf(-aR[ut][i]));  \
                const float zv = __builtin_amdgcn_rcpf(1.f + __expf(-aZ[ut][i]));  \
                const float npre = fmaf(rv, aNH[ut][i], aNX[ut][i]);          \
                const float nv =                                              \
                    1.f - 2.f * __builtin_amdgcn_rcpf(1.f + __expf(2.f * npre));   \
                const float hn = fmaf(zv, hp[ut][i] - nv, nv);                \
                hp[ut][i] = hn;                                               \
                hn4[i] = hn;                                                  \
            }                                                                 \
            hh[ut][0] = packrtz(hn4[0], hn4[1]);                              \
            hh[ut][1] = packrtz(hn4[2], hn4[3]);                              \
            *(f32x4*)(out + ((T) * BATCH + brow0 + b) * 64                    \
                          + 16 * ut + 4 * g4) = hn4;                          \
        }                                                                     \
    } while (0)

    #pragma unroll 1
    for (int t = 0; t < T_STEPS; t += 2) {
        STEP(t,     xb0);
        STEP(t + 1, xb1);
    }

    // h_last
    #pragma unroll
    for (int ut = 0; ut < 4; ++ut)
        *(f32x4*)(out + T_STEPS * BATCH * 64 + (brow0 + b) * 64
                      + 16 * ut + 4 * g4) = hp[ut];

#undef STEP
#undef ISSUE_X
}

extern "C" void kernel_launch(void* const* d_in, const int* in_sizes, int n_in,
                              void* d_out, int out_size, void* d_ws, size_t ws_size,
                              hipStream_t stream) {
    const float* X    = (const float*)d_in[0];
    const float* W_ih = (const float*)d_in[1];
    const float* W_hh = (const float*)d_in[2];
    const float* b_ih = (const float*)d_in[3];
    const float* b_hh = (const float*)d_in[4];
    float* out = (float*)d_out;

    dim3 grid(BATCH / 16);   // 64 blocks
    dim3 block(64);          // 1 wave
    gru_1wave_kernel<<<grid, block, 0, stream>>>(X, W_ih, W_hh, b_ih, b_hh, out);
}

// Round 7
// 652.489 us; speedup vs baseline: 1.1750x; 1.1750x over previous
//
#include <hip/hip_runtime.h>

// GRU, fp16 MFMA + fp32 accum, T=512 B=1024 I=H=64.
// Round 7: R3 core (best: 344us) + SIMD wave-pairing + arithmetic folds.
// Evidence model from R3/R6: t_step = F*issue + S_exch with F~2.9 (single
// wave/SIMD cadence+latency exposure), S_exch~740. Fix: 32 blocks x 512
// threads; waves 0-3 process batch-tile A, waves 4-7 tile B -> each SIMD
// (wid&3) hosts one A-wave + one B-wave, filling each other's issue gaps
// and exchange stalls. Per-wave stream identical to R3.
// Folds: r/z weight frags+biases pre-scaled by -log2e, n-side by +2*log2e
// => combine uses raw exp2f (v_exp_f32), no pre-multiplies (exact identity).
// x fp32->fp16 via v_cvt_pkrtz (R6 showed RTZ pack: absmax unchanged).
// C-layout (verified R3): col(unit)=lane&15, row(batch)=(lane>>4)*4+reg.

typedef _Float16 half8  __attribute__((ext_vector_type(8)));
typedef __fp16   fp16x2 __attribute__((ext_vector_type(2)));
typedef float    f32x4  __attribute__((ext_vector_type(4)));
typedef int      i32x4  __attribute__((ext_vector_type(4)));

#define T_STEPS 512
#define BATCH   1024
#define LOG2E   1.4426950408889634f

struct XBuf { float4 a0, a1, b0, b1; };

__device__ __forceinline__ int pk2(float x, float y) {
    fp16x2 p = __builtin_amdgcn_cvt_pkrtz(x, y);
    return __builtin_bit_cast(int, p);
}

// fp32x8 -> fp16x8 via 4x v_cvt_pkrtz
__device__ __forceinline__ half8 cvt8p(const float4& a, const float4& b) {
    i32x4 v;
    v[0] = pk2(a.x, a.y); v[1] = pk2(a.z, a.w);
    v[2] = pk2(b.x, b.y); v[3] = pk2(b.z, b.w);
    return __builtin_bit_cast(half8, v);
}

// load 8 floats, scale, convert to fp16x8 (init-time only)
__device__ __forceinline__ half8 loadw8s(const float* p, float s) {
    const float4* q = (const float4*)p;
    float4 a = q[0], b = q[1];
    a.x *= s; a.y *= s; a.z *= s; a.w *= s;
    b.x *= s; b.y *= s; b.z *= s; b.w *= s;
    half8 h;
    h[0] = (_Float16)a.x; h[1] = (_Float16)a.y; h[2] = (_Float16)a.z; h[3] = (_Float16)a.w;
    h[4] = (_Float16)b.x; h[5] = (_Float16)b.y; h[6] = (_Float16)b.z; h[7] = (_Float16)b.w;
    return h;
}

__device__ __forceinline__ void block_sync() {
    asm volatile("s_waitcnt lgkmcnt(0)" ::: "memory");
    __builtin_amdgcn_s_barrier();
    asm volatile("" ::: "memory");
}

#define MFMA16(A, B, C) __builtin_amdgcn_mfma_f32_16x16x32_f16((A), (B), (C), 0, 0, 0)

__global__ __launch_bounds__(512, 1)
void gru_pair_kernel(const float* __restrict__ X,     // [T,B,64]
                     const float* __restrict__ W_ih,  // [192,64]
                     const float* __restrict__ W_hh,  // [192,64]
                     const float* __restrict__ b_ih,  // [192]
                     const float* __restrict__ b_hh,  // [192]
                     float* __restrict__ out)         // [T*B*64] ++ [B*64]
{
    const int tid   = threadIdx.x;
    const int wid   = tid >> 6;        // 0..7; SIMD = wid&3
    const int wq    = wid & 3;         // unit group within tile
    const int tile  = wid >> 2;        // 0: waves0-3, 1: waves4-7
    const int l     = tid & 63;
    const int c     = l & 15;          // A-row / B-col / C-col
    const int g4    = l >> 4;          // lane group
    const int u     = wq * 16 + c;     // hidden-unit column
    const int row   = c;               // batch row within tile
    const int brow0 = blockIdx.x * 32 + tile * 16;

    __shared__ __align__(16) _Float16 hbuf[2][2][16][72];  // [tile][phase]

    const float sRZ = -LOG2E;          // sigmoid: rcp(1+exp2(-log2e*x))
    const float sN  = 2.0f * LOG2E;    // tanh: 1-2*rcp(exp2(2*log2e*x)+1)

    // ---- B-fragments (W columns), fp16, pre-scaled, loaded once ----
    const half8 Brx0 = loadw8s(W_ih + (u)       * 64 +  0 + 8 * g4, sRZ);
    const half8 Brx1 = loadw8s(W_ih + (u)       * 64 + 32 + 8 * g4, sRZ);
    const half8 Brh0 = loadw8s(W_hh + (u)       * 64 +  0 + 8 * g4, sRZ);
    const half8 Brh1 = loadw8s(W_hh + (u)       * 64 + 32 + 8 * g4, sRZ);
    const half8 Bzx0 = loadw8s(W_ih + (64 + u)  * 64 +  0 + 8 * g4, sRZ);
    const half8 Bzx1 = loadw8s(W_ih + (64 + u)  * 64 + 32 + 8 * g4, sRZ);
    const half8 Bzh0 = loadw8s(W_hh + (64 + u)  * 64 +  0 + 8 * g4, sRZ);
    const half8 Bzh1 = loadw8s(W_hh + (64 + u)  * 64 + 32 + 8 * g4, sRZ);
    const half8 Bnx0 = loadw8s(W_ih + (128 + u) * 64 +  0 + 8 * g4, sN);
    const half8 Bnx1 = loadw8s(W_ih + (128 + u) * 64 + 32 + 8 * g4, sN);
    const half8 Bnh0 = loadw8s(W_hh + (128 + u) * 64 +  0 + 8 * g4, sN);
    const half8 Bnh1 = loadw8s(W_hh + (128 + u) * 64 + 32 + 8 * g4, sN);

    const float rb  = sRZ * (b_ih[u]      + b_hh[u]);
    const float zb  = sRZ * (b_ih[64 + u] + b_hh[64 + u]);
    const float nxb = sN * b_ih[128 + u];
    const float nhb = sN * b_hh[128 + u];

    f32x4 hp = {0.f, 0.f, 0.f, 0.f};   // h (true scale), C-layout

#define ISSUE_X(XB, T) do {                                                   \
        const float* px_ = X + ((T) * BATCH + brow0 + row) * 64 + 8 * g4;     \
        (XB).a0 = ((const float4*)px_)[0];                                    \
        (XB).a1 = ((const float4*)px_)[1];                                    \
        (XB).b0 = ((const float4*)(px_ + 32))[0];                             \
        (XB).b1 = ((const float4*)(px_ + 32))[1];                             \
    } while (0)

    XBuf xb0, xb1;
    ISSUE_X(xb0, 0);
    ISSUE_X(xb1, 1);

    // zero h(t=0) buffers
    for (int k = tid; k < 2 * 2 * 16 * 72; k += 512)
        ((_Float16*)hbuf)[k] = (_Float16)0.f;
    __syncthreads();

#define STEP(T, XB) do {                                                      \
        const int p_ = (T) & 1;                                               \
        const half8 hf0 = *(const half8*)&hbuf[tile][p_][row][8 * g4];        \
        const half8 hf1 = *(const half8*)&hbuf[tile][p_][row][32 + 8 * g4];   \
        const half8 xf0 = cvt8p((XB).a0, (XB).a1);                            \
        const half8 xf1 = cvt8p((XB).b0, (XB).b1);                            \
        { int tn_ = (T) + 2; if (tn_ > T_STEPS - 1) tn_ = T_STEPS - 1;        \
          ISSUE_X(XB, tn_); }                                                 \
        f32x4 cr  = {rb, rb, rb, rb};                                         \
        f32x4 cz  = {zb, zb, zb, zb};                                         \
        f32x4 cnx = {nxb, nxb, nxb, nxb};                                     \
        f32x4 cnh = {nhb, nhb, nhb, nhb};                                     \
        cr  = MFMA16(xf0, Brx0, cr);  cr  = MFMA16(xf1, Brx1, cr);            \
        cz  = MFMA16(xf0, Bzx0, cz);  cz  = MFMA16(xf1, Bzx1, cz);            \
        cnx = MFMA16(xf0, Bnx0, cnx); cnx = MFMA16(xf1, Bnx1, cnx);           \
        cr  = MFMA16(hf0, Brh0, cr);  cr  = MFMA16(hf1, Brh1, cr);            \
        cz  = MFMA16(hf0, Bzh0, cz);  cz  = MFMA16(hf1, Bzh1, cz);            \
        cnh = MFMA16(hf0, Bnh0, cnh); cnh = MFMA16(hf1, Bnh1, cnh);           \
        _Pragma("unroll")                                                     \
        for (int i = 0; i < 4; ++i) {                                         \
            const float rv = __builtin_amdgcn_rcpf(1.f + exp2f(cr[i]));       \
            const float zv = __builtin_amdgcn_rcpf(1.f + exp2f(cz[i]));       \
            const float npre = fmaf(rv, cnh[i], cnx[i]);                      \
            const float e  = exp2f(npre);                                     \
            const float nv = 1.f - 2.f * __builtin_amdgcn_rcpf(e + 1.f);      \
            const float hn = fmaf(zv, hp[i] - nv, nv);                        \
            hp[i] = hn;                                                       \
            hbuf[tile][p_ ^ 1][4 * g4 + i][u] = (_Float16)hn;                 \
            out[((T) * BATCH + brow0 + 4 * g4 + i) * 64 + u] = hn;            \
        }                                                                     \
        block_sync();                                                         \
    } while (0)

    #pragma unroll 1
    for (int t = 0; t < T_STEPS; t += 2) {
        STEP(t, xb0);
        STEP(t + 1, xb1);
    }

    #pragma unroll
    for (int i = 0; i < 4; ++i)
        out[T_STEPS * BATCH * 64 + (brow0 + 4 * g4 + i) * 64 + u] = hp[i];

#undef STEP
#undef ISSUE_X
}

extern "C" void kernel_launch(void* const* d_in, const int* in_sizes, int n_in,
                              void* d_out, int out_size, void* d_ws, size_t ws_size,
                              hipStream_t stream) {
    const float* X    = (const float*)d_in[0];
    const float* W_ih = (const float*)d_in[1];
    const float* W_hh = (const float*)d_in[2];
    const float* b_ih = (const float*)d_in[3];
    const float* b_hh = (const float*)d_in[4];
    float* out = (float*)d_out;

    dim3 grid(BATCH / 32);   // 32 blocks, 2 batch-tiles each
    dim3 block(512);         // 8 waves: 2 per SIMD
    gru_pair_kernel<<<grid, block, 0, stream>>>(X, W_ih, W_hh, b_ih, b_hh, out);
}

// Round 8
// 579.808 us; speedup vs baseline: 1.3223x; 1.1254x over previous
//
#include <hip/hip_runtime.h>

// GRU, fp16 MFMA + fp32 accum, T=512 B=1024 I=H=64.
// Round 8: two-phase. Phase 1 (full chip, ~32768 blocks): precompute
// gx[t] = scale*(W_ih x_t + bias) fp16 in d_ws, laid out per-lane for the
// recurrence. Phase 2 (64 blocks x 4 waves, R3 structure): h-side only --
// 6 MFMAs/step, gx loaded as C-init via 3x b64 loads (2-step prefetch).
// Rationale: R3/R7 VGPR_Count (96/76) << static demand (~150+) => compiler
// spills W frags / x bufs in-loop; scratch round trips explain the ~1400
// cyc/step unexplained stall. This version's live set ~90 VGPR: no spill.
// log2e folded into weights/biases (R7-validated): sigmoid via exp2, tanh
// via exp2(2*log2e*x).
// C-layout (verified R3/R6): col=lane&15, row=(lane>>4)*4+reg.

typedef _Float16 half8  __attribute__((ext_vector_type(8)));
typedef __fp16   fp16x2 __attribute__((ext_vector_type(2)));
typedef float    f32x4  __attribute__((ext_vector_type(4)));
typedef int      i32x4  __attribute__((ext_vector_type(4)));

#define T_STEPS 512
#define BATCH   1024
#define LOG2E   1.4426950408889634f

__device__ __forceinline__ int pk2(float x, float y) {
    fp16x2 p = __builtin_amdgcn_cvt_pkrtz(x, y);
    return __builtin_bit_cast(int, p);
}

__device__ __forceinline__ half8 cvt8p(const float4& a, const float4& b) {
    i32x4 v;
    v[0] = pk2(a.x, a.y); v[1] = pk2(a.z, a.w);
    v[2] = pk2(b.x, b.y); v[3] = pk2(b.z, b.w);
    return __builtin_bit_cast(half8, v);
}

__device__ __forceinline__ half8 loadw8s(const float* p, float s) {
    const float4* q = (const float4*)p;
    float4 a = q[0], b = q[1];
    half8 h;
    h[0] = (_Float16)(a.x * s); h[1] = (_Float16)(a.y * s);
    h[2] = (_Float16)(a.z * s); h[3] = (_Float16)(a.w * s);
    h[4] = (_Float16)(b.x * s); h[5] = (_Float16)(b.y * s);
    h[6] = (_Float16)(b.z * s); h[7] = (_Float16)(b.w * s);
    return h;
}

__device__ __forceinline__ f32x4 cvtgx(uint2 v) {
    fp16x2 p0 = __builtin_bit_cast(fp16x2, v.x);
    fp16x2 p1 = __builtin_bit_cast(fp16x2, v.y);
    f32x4 r;
    r[0] = (float)p0[0]; r[1] = (float)p0[1];
    r[2] = (float)p1[0]; r[3] = (float)p1[1];
    return r;
}

__device__ __forceinline__ void block_sync() {
    asm volatile("s_waitcnt lgkmcnt(0)" ::: "memory");
    __builtin_amdgcn_s_barrier();
    asm volatile("" ::: "memory");
}

#define MFMA16(A, B, C) __builtin_amdgcn_mfma_f32_16x16x32_f16((A), (B), (C), 0, 0, 0)

// ---------------- Phase 1: gx precompute ----------------
// gx layout: [t][tile(64)][grow(192)][brow(16)] fp16, grow = g*64+u.
// gx = scale(grow) * (W_ih x + bias), bias = b_ih+b_hh for r/z, b_ih for n.
__global__ __launch_bounds__(256, 1)
void gru_gx_kernel(const float* __restrict__ X,     // [T,B,64]
                   const float* __restrict__ W_ih,  // [192,64]
                   const float* __restrict__ b_ih,
                   const float* __restrict__ b_hh,
                   _Float16* __restrict__ gx)
{
    const int tid  = threadIdx.x;
    const int wq   = tid >> 6;
    const int l    = tid & 63;
    const int c    = l & 15;
    const int g4   = l >> 4;
    const int bid  = blockIdx.x;      // t*64 + tile
    const int t    = bid >> 6;
    const int b0   = (bid & 63) * 16;

    // B-frags from x: col=batch(c), k=8*g4+e
    const float* px = X + ((size_t)t * BATCH + b0 + c) * 64 + 8 * g4;
    const float4 xa0 = ((const float4*)px)[0];
    const float4 xa1 = ((const float4*)px)[1];
    const float4 xb0 = ((const float4*)(px + 32))[0];
    const float4 xb1 = ((const float4*)(px + 32))[1];
    const half8 Bx0 = cvt8p(xa0, xa1);
    const half8 Bx1 = cvt8p(xb0, xb1);

    // 3 C-tiles per wave: gate rows [48wq, 48wq+48)
    #pragma unroll
    for (int ut2 = 0; ut2 < 3; ++ut2) {
        const int grow0 = 48 * wq + 16 * ut2;   // multiple of 16; no straddle of 128
        const int arow  = grow0 + c;
        const float sA  = (arow < 128) ? -LOG2E : 2.0f * LOG2E;
        const half8 A0 = loadw8s(W_ih + arow * 64 + 8 * g4, sA);
        const half8 A1 = loadw8s(W_ih + arow * 64 + 32 + 8 * g4, sA);
        f32x4 acc;
        #pragma unroll
        for (int i = 0; i < 4; ++i) {
            const int grow = grow0 + 4 * g4 + i;
            const float sc = (grow < 128) ? -LOG2E : 2.0f * LOG2E;
            const float bias = (grow < 128) ? (b_ih[grow] + b_hh[grow]) : b_ih[grow];
            acc[i] = sc * bias;
        }
        acc = MFMA16(A0, Bx0, acc);
        acc = MFMA16(A1, Bx1, acc);
        #pragma unroll
        for (int i = 0; i < 4; ++i) {
            const int grow = grow0 + 4 * g4 + i;
            gx[((size_t)bid * 192 + grow) * 16 + c] = (_Float16)acc[i];
        }
    }
}

// ---------------- Phase 2: recurrence ----------------
struct GxB { uint2 r, z, n; };
struct XBuf { float4 a0, a1, b0, b1; };

template<bool USE_GX>
__global__ __launch_bounds__(256, 1)
void gru_rec_kernel(const float* __restrict__ X,
                    const float* __restrict__ W_ih,
                    const float* __restrict__ W_hh,
                    const float* __restrict__ b_ih,
                    const float* __restrict__ b_hh,
                    const _Float16* __restrict__ gx,
                    float* __restrict__ out)
{
    const int tid   = threadIdx.x;
    const int wq    = tid >> 6;       // unit group
    const int l     = tid & 63;
    const int c     = l & 15;
    const int g4    = l >> 4;
    const int u     = wq * 16 + c;
    const int brow0 = blockIdx.x * 16;

    __shared__ __align__(16) _Float16 hbuf[2][16][72];

    const float sRZ = -LOG2E;
    const float sN  = 2.0f * LOG2E;

    // h-side W frags (pre-scaled), 24 VGPR
    const half8 Brh0 = loadw8s(W_hh + (u)       * 64 +      8 * g4, sRZ);
    const half8 Brh1 = loadw8s(W_hh + (u)       * 64 + 32 + 8 * g4, sRZ);
    const half8 Bzh0 = loadw8s(W_hh + (64 + u)  * 64 +      8 * g4, sRZ);
    const half8 Bzh1 = loadw8s(W_hh + (64 + u)  * 64 + 32 + 8 * g4, sRZ);
    const half8 Bnh0 = loadw8s(W_hh + (128 + u) * 64 +      8 * g4, sN);
    const half8 Bnh1 = loadw8s(W_hh + (128 + u) * 64 + 32 + 8 * g4, sN);
    const float nhb  = sN * b_hh[128 + u];

    // x-side (fallback only)
    half8 Brx0, Brx1, Bzx0, Bzx1, Bnx0, Bnx1;
    float rb = 0.f, zb = 0.f, nxb = 0.f;
    if (!USE_GX) {
        Brx0 = loadw8s(W_ih + (u)       * 64 +      8 * g4, sRZ);
        Brx1 = loadw8s(W_ih + (u)       * 64 + 32 + 8 * g4, sRZ);
        Bzx0 = loadw8s(W_ih + (64 + u)  * 64 +      8 * g4, sRZ);
        Bzx1 = loadw8s(W_ih + (64 + u)  * 64 + 32 + 8 * g4, sRZ);
        Bnx0 = loadw8s(W_ih + (128 + u) * 64 +      8 * g4, sN);
        Bnx1 = loadw8s(W_ih + (128 + u) * 64 + 32 + 8 * g4, sN);
        rb  = sRZ * (b_ih[u]      + b_hh[u]);
        zb  = sRZ * (b_ih[64 + u] + b_hh[64 + u]);
        nxb = sN * b_ih[128 + u];
    }

    // gx per-lane pointers (GX path): stride per t = 64*192*16 halves
    const size_t tstride = (size_t)64 * 192 * 16;
    const _Float16* gpr = gx + ((size_t)blockIdx.x * 192 + 0   + u) * 16 + 4 * g4;
    const _Float16* gpz = gx + ((size_t)blockIdx.x * 192 + 64  + u) * 16 + 4 * g4;
    const _Float16* gpn = gx + ((size_t)blockIdx.x * 192 + 128 + u) * 16 + 4 * g4;

    GxB ga, gb;
    XBuf xa;
    if (USE_GX) {
        ga.r = *(const uint2*)(gpr);            ga.z = *(const uint2*)(gpz);
        ga.n = *(const uint2*)(gpn);
        gb.r = *(const uint2*)(gpr + tstride);  gb.z = *(const uint2*)(gpz + tstride);
        gb.n = *(const uint2*)(gpn + tstride);
    } else {
        const float* px_ = X + ((size_t)0 * BATCH + brow0 + c) * 64 + 8 * g4;
        xa.a0 = ((const float4*)px_)[0]; xa.a1 = ((const float4*)px_)[1];
        xa.b0 = ((const float4*)(px_ + 32))[0]; xa.b1 = ((const float4*)(px_ + 32))[1];
    }

    // zero h(0) buffers
    for (int k = tid; k < 2 * 16 * 72; k += 256)
        ((_Float16*)hbuf)[k] = (_Float16)0.f;
    __syncthreads();

    f32x4 hp = {0.f, 0.f, 0.f, 0.f};

#define STEP(T, GA, GB) do {                                                  \
        const int p_ = (T) & 1;                                               \
        const half8 hf0 = *(const half8*)&hbuf[p_][c][8 * g4];                \
        const half8 hf1 = *(const half8*)&hbuf[p_][c][32 + 8 * g4];           \
        f32x4 cr, cz, cnx;                                                    \
        half8 xf0, xf1;                                                       \
        if (USE_GX) {                                                         \
            cr = cvtgx(GA.r); cz = cvtgx(GA.z); cnx = cvtgx(GA.n);            \
            const size_t to_ = (size_t)(((T) + 2 <= T_STEPS - 1) ? (T) + 2    \
                                        : T_STEPS - 1) * tstride;             \
            GA.r = *(const uint2*)(gpr + to_);                                \
            GA.z = *(const uint2*)(gpz + to_);                                \
            GA.n = *(const uint2*)(gpn + to_);                                \
        } else {                                                              \
            xf0 = cvt8p(xa.a0, xa.a1); xf1 = cvt8p(xa.b0, xa.b1);             \
            const int tn_ = ((T) + 1 <= T_STEPS - 1) ? (T) + 1 : T_STEPS - 1; \
            const float* px_ = X + ((size_t)tn_ * BATCH + brow0 + c) * 64     \
                                 + 8 * g4;                                    \
            xa.a0 = ((const float4*)px_)[0]; xa.a1 = ((const float4*)px_)[1]; \
            xa.b0 = ((const float4*)(px_ + 32))[0];                           \
            xa.b1 = ((const float4*)(px_ + 32))[1];                           \
            cr = (f32x4){rb, rb, rb, rb};                                     \
            cz = (f32x4){zb, zb, zb, zb};                                     \
            cnx = (f32x4){nxb, nxb, nxb, nxb};                                \
            cr  = MFMA16(xf0, Brx0, cr);  cr  = MFMA16(xf1, Brx1, cr);        \
            cz  = MFMA16(xf0, Bzx0, cz);  cz  = MFMA16(xf1, Bzx1, cz);        \
            cnx = MFMA16(xf0, Bnx0, cnx); cnx = MFMA16(xf1, Bnx1, cnx);       \
        }                                                                     \
        f32x4 cnh = {nhb, nhb, nhb, nhb};                                     \
        cr  = MFMA16(hf0, Brh0, cr);  cr  = MFMA16(hf1, Brh1, cr);            \
        cz  = MFMA16(hf0, Bzh0, cz);  cz  = MFMA16(hf1, Bzh1, cz);            \
        cnh = MFMA16(hf0, Bnh0, cnh); cnh = MFMA16(hf1, Bnh1, cnh);           \
        _Pragma("unroll")                                                     \
        for (int i = 0; i < 4; ++i) {                                         \
            const float rv = __builtin_amdgcn_rcpf(1.f + exp2f(cr[i]));       \
            const float zv = __builtin_amdgcn_rcpf(1.f + exp2f(cz[i]));       \
            const float npre = fmaf(rv, cnh[i], cnx[i]);                      \
            const float e  = exp2f(npre);                                     \
            const float nv = 1.f - 2.f * __builtin_amdgcn_rcpf(e + 1.f);      \
            const float hn = fmaf(zv, hp[i] - nv, nv);                        \
            hp[i] = hn;                                                       \
            hbuf[p_ ^ 1][4 * g4 + i][u] = (_Float16)hn;                       \
            out[((size_t)(T) * BATCH + brow0 + 4 * g4 + i) * 64 + u] = hn;    \
        }                                                                     \
        block_sync();                                                         \
    } while (0)

    #pragma unroll 1
    for (int t = 0; t < T_STEPS; t += 2) {
        STEP(t,     ga, gb);
        STEP(t + 1, gb, ga);
    }

    #pragma unroll
    for (int i = 0; i < 4; ++i)
        out[(size_t)T_STEPS * BATCH * 64 + (brow0 + 4 * g4 + i) * 64 + u] = hp[i];

#undef STEP
}

extern "C" void kernel_launch(void* const* d_in, const int* in_sizes, int n_in,
                              void* d_out, int out_size, void* d_ws, size_t ws_size,
                              hipStream_t stream) {
    const float* X    = (const float*)d_in[0];
    const float* W_ih = (const float*)d_in[1];
    const float* W_hh = (const float*)d_in[2];
    const float* b_ih = (const float*)d_in[3];
    const float* b_hh = (const float*)d_in[4];
    float* out = (float*)d_out;

    const size_t GX_BYTES = (size_t)T_STEPS * 64 * 192 * 16 * 2;  // 192 MiB
    if (ws_size >= GX_BYTES) {
        _Float16* gxw = (_Float16*)d_ws;
        gru_gx_kernel<<<dim3(T_STEPS * 64), dim3(256), 0, stream>>>(
            X, W_ih, b_ih, b_hh, gxw);
        gru_rec_kernel<true><<<dim3(BATCH / 16), dim3(256), 0, stream>>>(
            X, W_ih, W_hh, b_ih, b_hh, gxw, out);
    } else {
        gru_rec_kernel<false><<<dim3(BATCH / 16), dim3(256), 0, stream>>>(
            X, W_ih, W_hh, b_ih, b_hh, (const _Float16*)nullptr, out);
    }
}

// Round 10
// 440.688 us; speedup vs baseline: 1.7397x; 1.3157x over previous
//
#include <hip/hip_runtime.h>

// GRU, fp16 MFMA + fp32 accum, T=512 B=1024 I=H=64.
// Round 10 = R8's VERIFIED rec kernel (315us, absmax 0.0039) + gx v2
// (16 timesteps/block, W loaded once per block, 2048 blocks -- R8's gx did
// 1 t/block and burned ~260us on per-block W reload overhead).
// R9's tr_b16 exchange is REVERTED (failed absmax 0.67: k-map wrong).
// This round isolates gx v2 correctness: layout is identical to R8's gx,
// only the t-loop is new.
// log2e folded into weights/biases: sigmoid via exp2, tanh via exp2(2x*log2e).
// C-layout (verified R3..R8): col=lane&15, row=(lane>>4)*4+reg.

typedef _Float16 half8  __attribute__((ext_vector_type(8)));
typedef __fp16   fp16x2 __attribute__((ext_vector_type(2)));
typedef float    f32x4  __attribute__((ext_vector_type(4)));
typedef int      i32x4  __attribute__((ext_vector_type(4)));

#define T_STEPS 512
#define BATCH   1024
#define LOG2E   1.4426950408889634f

struct XBuf { float4 a0, a1, b0, b1; };
struct GxB  { uint2 r, z, n; };

__device__ __forceinline__ int pk2(float x, float y) {
    fp16x2 p = __builtin_amdgcn_cvt_pkrtz(x, y);
    return __builtin_bit_cast(int, p);
}

__device__ __forceinline__ half8 cvt8p(const float4& a, const float4& b) {
    i32x4 v;
    v[0] = pk2(a.x, a.y); v[1] = pk2(a.z, a.w);
    v[2] = pk2(b.x, b.y); v[3] = pk2(b.z, b.w);
    return __builtin_bit_cast(half8, v);
}

__device__ __forceinline__ half8 loadw8s(const float* p, float s) {
    const float4* q = (const float4*)p;
    float4 a = q[0], b = q[1];
    half8 h;
    h[0] = (_Float16)(a.x * s); h[1] = (_Float16)(a.y * s);
    h[2] = (_Float16)(a.z * s); h[3] = (_Float16)(a.w * s);
    h[4] = (_Float16)(b.x * s); h[5] = (_Float16)(b.y * s);
    h[6] = (_Float16)(b.z * s); h[7] = (_Float16)(b.w * s);
    return h;
}

__device__ __forceinline__ f32x4 cvtgx(uint2 v) {
    fp16x2 p0 = __builtin_bit_cast(fp16x2, v.x);
    fp16x2 p1 = __builtin_bit_cast(fp16x2, v.y);
    f32x4 r;
    r[0] = (float)p0[0]; r[1] = (float)p0[1];
    r[2] = (float)p1[0]; r[3] = (float)p1[1];
    return r;
}

__device__ __forceinline__ void block_sync() {
    asm volatile("s_waitcnt lgkmcnt(0)" ::: "memory");
    __builtin_amdgcn_s_barrier();
    asm volatile("" ::: "memory");
}

#define MFMA16(A, B, C) __builtin_amdgcn_mfma_f32_16x16x32_f16((A), (B), (C), 0, 0, 0)

// ---------------- Phase 1: gx precompute (v2: 16 t per block) ----------------
// gx layout: [t][tile(64)][grow(192)][brow(16)] fp16  (identical to R8).
#define GX_NT 16
__global__ __launch_bounds__(256, 1)
void gru_gx_kernel(const float* __restrict__ X,     // [T,B,64]
                   const float* __restrict__ W_ih,  // [192,64]
                   const float* __restrict__ b_ih,
                   const float* __restrict__ b_hh,
                   _Float16* __restrict__ gx)
{
    const int tid  = threadIdx.x;
    const int wq   = tid >> 6;
    const int l    = tid & 63;
    const int c    = l & 15;
    const int g4   = l >> 4;
    const int tile = blockIdx.x & 63;
    const int tc   = blockIdx.x >> 6;          // 32 chunks of 16 t
    const int b0   = tile * 16;
    const int t0   = tc * GX_NT;

    // A-frags (W_ih rows, scaled) + bias inits: loaded ONCE per block
    half8 A0[3], A1[3];
    f32x4 binit[3];
    #pragma unroll
    for (int ut2 = 0; ut2 < 3; ++ut2) {
        const int grow0 = 48 * wq + 16 * ut2;
        const int arow  = grow0 + c;
        const float sA  = (arow < 128) ? -LOG2E : 2.0f * LOG2E;
        A0[ut2] = loadw8s(W_ih + arow * 64 + 8 * g4, sA);
        A1[ut2] = loadw8s(W_ih + arow * 64 + 32 + 8 * g4, sA);
        #pragma unroll
        for (int i = 0; i < 4; ++i) {
            const int grow = grow0 + 4 * g4 + i;
            const float sc = (grow < 128) ? -LOG2E : 2.0f * LOG2E;
            const float bias = (grow < 128) ? (b_ih[grow] + b_hh[grow]) : b_ih[grow];
            binit[ut2][i] = sc * bias;
        }
    }

#define GX_ISSUE_X(XB, T) do {                                                \
        const float* px_ = X + ((size_t)(T) * BATCH + b0 + c) * 64 + 8 * g4;  \
        (XB).a0 = ((const float4*)px_)[0];                                    \
        (XB).a1 = ((const float4*)px_)[1];                                    \
        (XB).b0 = ((const float4*)(px_ + 32))[0];                             \
        (XB).b1 = ((const float4*)(px_ + 32))[1];                             \
    } while (0)

    XBuf xb0, xb1;
    GX_ISSUE_X(xb0, t0);
    GX_ISSUE_X(xb1, t0 + 1);

#define GX_STEP(T, XB) do {                                                   \
        const half8 Bx0 = cvt8p((XB).a0, (XB).a1);                            \
        const half8 Bx1 = cvt8p((XB).b0, (XB).b1);                            \
        { int tn_ = (T) + 2; if (tn_ > T_STEPS - 1) tn_ = T_STEPS - 1;        \
          GX_ISSUE_X(XB, tn_); }                                              \
        _Float16* gbase = gx + ((size_t)((T) * 64 + tile) * 192) * 16;        \
        _Pragma("unroll")                                                     \
        for (int ut2 = 0; ut2 < 3; ++ut2) {                                   \
            f32x4 acc = binit[ut2];                                           \
            acc = MFMA16(A0[ut2], Bx0, acc);                                  \
            acc = MFMA16(A1[ut2], Bx1, acc);                                  \
            const int grow0 = 48 * wq + 16 * ut2;                             \
            _Pragma("unroll")                                                 \
            for (int i = 0; i < 4; ++i)                                       \
                gbase[(size_t)(grow0 + 4 * g4 + i) * 16 + c] = (_Float16)acc[i]; \
        }                                                                     \
    } while (0)

    #pragma unroll 1
    for (int it = 0; it < GX_NT; it += 2) {
        GX_STEP(t0 + it,     xb0);
        GX_STEP(t0 + it + 1, xb1);
    }
#undef GX_STEP
#undef GX_ISSUE_X
}

// ---------------- Phase 2: recurrence (R8 VERBATIM) ----------------
template<bool USE_GX>
__global__ __launch_bounds__(256, 1)
void gru_rec_kernel(const float* __restrict__ X,
                    const float* __restrict__ W_ih,
                    const float* __restrict__ W_hh,
                    const float* __restrict__ b_ih,
                    const float* __restrict__ b_hh,
                    const _Float16* __restrict__ gx,
                    float* __restrict__ out)
{
    const int tid   = threadIdx.x;
    const int wq    = tid >> 6;       // unit group
    const int l     = tid & 63;
    const int c     = l & 15;
    const int g4    = l >> 4;
    const int u     = wq * 16 + c;
    const int brow0 = blockIdx.x * 16;

    __shared__ __align__(16) _Float16 hbuf[2][16][72];

    const float sRZ = -LOG2E;
    const float sN  = 2.0f * LOG2E;

    // h-side W frags (pre-scaled), 24 VGPR
    const half8 Brh0 = loadw8s(W_hh + (u)       * 64 +      8 * g4, sRZ);
    const half8 Brh1 = loadw8s(W_hh + (u)       * 64 + 32 + 8 * g4, sRZ);
    const half8 Bzh0 = loadw8s(W_hh + (64 + u)  * 64 +      8 * g4, sRZ);
    const half8 Bzh1 = loadw8s(W_hh + (64 + u)  * 64 + 32 + 8 * g4, sRZ);
    const half8 Bnh0 = loadw8s(W_hh + (128 + u) * 64 +      8 * g4, sN);
    const half8 Bnh1 = loadw8s(W_hh + (128 + u) * 64 + 32 + 8 * g4, sN);
    const float nhb  = sN * b_hh[128 + u];

    // x-side (fallback only)
    half8 Brx0, Brx1, Bzx0, Bzx1, Bnx0, Bnx1;
    float rb = 0.f, zb = 0.f, nxb = 0.f;
    if (!USE_GX) {
        Brx0 = loadw8s(W_ih + (u)       * 64 +      8 * g4, sRZ);
        Brx1 = loadw8s(W_ih + (u)       * 64 + 32 + 8 * g4, sRZ);
        Bzx0 = loadw8s(W_ih + (64 + u)  * 64 +      8 * g4, sRZ);
        Bzx1 = loadw8s(W_ih + (64 + u)  * 64 + 32 + 8 * g4, sRZ);
        Bnx0 = loadw8s(W_ih + (128 + u) * 64 +      8 * g4, sN);
        Bnx1 = loadw8s(W_ih + (128 + u) * 64 + 32 + 8 * g4, sN);
        rb  = sRZ * (b_ih[u]      + b_hh[u]);
        zb  = sRZ * (b_ih[64 + u] + b_hh[64 + u]);
        nxb = sN * b_ih[128 + u];
    }

    // gx per-lane pointers (GX path): stride per t = 64*192*16 halves
    const size_t tstride = (size_t)64 * 192 * 16;
    const _Float16* gpr = gx + ((size_t)blockIdx.x * 192 + 0   + u) * 16 + 4 * g4;
    const _Float16* gpz = gx + ((size_t)blockIdx.x * 192 + 64  + u) * 16 + 4 * g4;
    const _Float16* gpn = gx + ((size_t)blockIdx.x * 192 + 128 + u) * 16 + 4 * g4;

    GxB ga, gb;
    XBuf xa;
    if (USE_GX) {
        ga.r = *(const uint2*)(gpr);            ga.z = *(const uint2*)(gpz);
        ga.n = *(const uint2*)(gpn);
        gb.r = *(const uint2*)(gpr + tstride);  gb.z = *(const uint2*)(gpz + tstride);
        gb.n = *(const uint2*)(gpn + tstride);
    } else {
        const float* px_ = X + ((size_t)0 * BATCH + brow0 + c) * 64 + 8 * g4;
        xa.a0 = ((const float4*)px_)[0]; xa.a1 = ((const float4*)px_)[1];
        xa.b0 = ((const float4*)(px_ + 32))[0]; xa.b1 = ((const float4*)(px_ + 32))[1];
    }

    // zero h(0) buffers
    for (int k = tid; k < 2 * 16 * 72; k += 256)
        ((_Float16*)hbuf)[k] = (_Float16)0.f;
    __syncthreads();

    f32x4 hp = {0.f, 0.f, 0.f, 0.f};

#define STEP(T, GA, GB) do {                                                  \
        const int p_ = (T) & 1;                                               \
        const half8 hf0 = *(const half8*)&hbuf[p_][c][8 * g4];                \
        const half8 hf1 = *(const half8*)&hbuf[p_][c][32 + 8 * g4];           \
        f32x4 cr, cz, cnx;                                                    \
        half8 xf0, xf1;                                                       \
        if (USE_GX) {                                                         \
            cr = cvtgx(GA.r); cz = cvtgx(GA.z); cnx = cvtgx(GA.n);            \
            const size_t to_ = (size_t)(((T) + 2 <= T_STEPS - 1) ? (T) + 2    \
                                        : T_STEPS - 1) * tstride;             \
            GA.r = *(const uint2*)(gpr + to_);                                \
            GA.z = *(const uint2*)(gpz + to_);                                \
            GA.n = *(const uint2*)(gpn + to_);                                \
        } else {                                                              \
            xf0 = cvt8p(xa.a0, xa.a1); xf1 = cvt8p(xa.b0, xa.b1);             \
            const int tn_ = ((T) + 1 <= T_STEPS - 1) ? (T) + 1 : T_STEPS - 1; \
            const float* px_ = X + ((size_t)tn_ * BATCH + brow0 + c) * 64     \
                                 + 8 * g4;                                    \
            xa.a0 = ((const float4*)px_)[0]; xa.a1 = ((const float4*)px_)[1]; \
            xa.b0 = ((const float4*)(px_ + 32))[0];                           \
            xa.b1 = ((const float4*)(px_ + 32))[1];                           \
            cr = (f32x4){rb, rb, rb, rb};                                     \
            cz = (f32x4){zb, zb, zb, zb};                                     \
            cnx = (f32x4){nxb, nxb, nxb, nxb};                                \
            cr  = MFMA16(xf0, Brx0, cr);  cr  = MFMA16(xf1, Brx1, cr);        \
            cz  = MFMA16(xf0, Bzx0, cz);  cz  = MFMA16(xf1, Bzx1, cz);        \
            cnx = MFMA16(xf0, Bnx0, cnx); cnx = MFMA16(xf1, Bnx1, cnx);       \
        }                                                                     \
        f32x4 cnh = {nhb, nhb, nhb, nhb};                                     \
        cr  = MFMA16(hf0, Brh0, cr);  cr  = MFMA16(hf1, Brh1, cr);            \
        cz  = MFMA16(hf0, Bzh0, cz);  cz  = MFMA16(hf1, Bzh1, cz);            \
        cnh = MFMA16(hf0, Bnh0, cnh); cnh = MFMA16(hf1, Bnh1, cnh);           \
        _Pragma("unroll")                                                     \
        for (int i = 0; i < 4; ++i) {                                         \
            const float rv = __builtin_amdgcn_rcpf(1.f + exp2f(cr[i]));       \
            const float zv = __builtin_amdgcn_rcpf(1.f + exp2f(cz[i]));       \
            const float npre = fmaf(rv, cnh[i], cnx[i]);                      \
            const float e  = exp2f(npre);                                     \
            const float nv = 1.f - 2.f * __builtin_amdgcn_rcpf(e + 1.f);      \
            const float hn = fmaf(zv, hp[i] - nv, nv);                        \
            hp[i] = hn;                                                       \
            hbuf[p_ ^ 1][4 * g4 + i][u] = (_Float16)hn;                       \
            out[((size_t)(T) * BATCH + brow0 + 4 * g4 + i) * 64 + u] = hn;    \
        }                                                                     \
        block_sync();                                                         \
    } while (0)

    #pragma unroll 1
    for (int t = 0; t < T_STEPS; t += 2) {
        STEP(t,     ga, gb);
        STEP(t + 1, gb, ga);
    }

    #pragma unroll
    for (int i = 0; i < 4; ++i)
        out[(size_t)T_STEPS * BATCH * 64 + (brow0 + 4 * g4 + i) * 64 + u] = hp[i];

#undef STEP
}

extern "C" void kernel_launch(void* const* d_in, const int* in_sizes, int n_in,
                              void* d_out, int out_size, void* d_ws, size_t ws_size,
                              hipStream_t stream) {
    const float* X    = (const float*)d_in[0];
    const float* W_ih = (const float*)d_in[1];
    const float* W_hh = (const float*)d_in[2];
    const float* b_ih = (const float*)d_in[3];
    const float* b_hh = (const float*)d_in[4];
    float* out = (float*)d_out;

    const size_t GX_BYTES = (size_t)T_STEPS * 64 * 192 * 16 * 2;  // 192 MiB
    if (ws_size >= GX_BYTES) {
        _Float16* gxw = (_Float16*)d_ws;
        gru_gx_kernel<<<dim3((T_STEPS / GX_NT) * 64), dim3(256), 0, stream>>>(
            X, W_ih, b_ih, b_hh, gxw);
        gru_rec_kernel<true><<<dim3(BATCH / 16), dim3(256), 0, stream>>>(
            X, W_ih, W_hh, b_ih, b_hh, gxw, out);
    } else {
        gru_rec_kernel<false><<<dim3(BATCH / 16), dim3(256), 0, stream>>>(
            X, W_ih, W_hh, b_ih, b_hh, (const _Float16*)nullptr, out);
    }
}

// Round 11
// 311.311 us; speedup vs baseline: 2.4628x; 1.4156x over previous
//
#include <hip/hip_runtime.h>

// GRU, fp16 MFMA + fp32 accum, T=512 B=1024 I=H=64.
// Round 11: single fused kernel = R10's verified rec structure with the
// x-side back in the loop, made cheap:
//  - 2-deep X prefetch (xb0/xb1), loads issued 2 steps early (off-path)
//  - x fp32->fp16 via 4x v_cvt_pkrtz (R3 paid 16 scalar v_cvt per step)
//  - log2e folded into weights/biases (R7/R8-validated): sigmoid/tanh via
//    raw exp2 (v_exp_f32), zero pre-multiplies in the combine
//  - x-MFMAs chained into cr/cz/cnx BEFORE the h-MFMAs: they issue and
//    execute inside the ds_read-h latency window (R3's proven ordering)
//  - exchange/combine/barrier verbatim from R10's 323us rec kernel.
// History: R3 fused=344 (steplat 1970), R8/R10 split rec=323 (1515) but
// gx dispatch cost 115-260 -> split never beat R3. This reclaims the
// fused form minus R3's x-side overhead. No workspace needed.
// C-layout (verified R3..R10): col(unit)=lane&15, row(batch)=(lane>>4)*4+reg.

typedef _Float16 half8  __attribute__((ext_vector_type(8)));
typedef __fp16   fp16x2 __attribute__((ext_vector_type(2)));
typedef float    f32x4  __attribute__((ext_vector_type(4)));
typedef int      i32x4  __attribute__((ext_vector_type(4)));

#define T_STEPS 512
#define BATCH   1024
#define LOG2E   1.4426950408889634f

struct XBuf { float4 a0, a1, b0, b1; };

__device__ __forceinline__ int pk2(float x, float y) {
    fp16x2 p = __builtin_amdgcn_cvt_pkrtz(x, y);
    return __builtin_bit_cast(int, p);
}

__device__ __forceinline__ half8 cvt8p(const float4& a, const float4& b) {
    i32x4 v;
    v[0] = pk2(a.x, a.y); v[1] = pk2(a.z, a.w);
    v[2] = pk2(b.x, b.y); v[3] = pk2(b.z, b.w);
    return __builtin_bit_cast(half8, v);
}

__device__ __forceinline__ half8 loadw8s(const float* p, float s) {
    const float4* q = (const float4*)p;
    float4 a = q[0], b = q[1];
    half8 h;
    h[0] = (_Float16)(a.x * s); h[1] = (_Float16)(a.y * s);
    h[2] = (_Float16)(a.z * s); h[3] = (_Float16)(a.w * s);
    h[4] = (_Float16)(b.x * s); h[5] = (_Float16)(b.y * s);
    h[6] = (_Float16)(b.z * s); h[7] = (_Float16)(b.w * s);
    return h;
}

__device__ __forceinline__ void block_sync() {
    asm volatile("s_waitcnt lgkmcnt(0)" ::: "memory");
    __builtin_amdgcn_s_barrier();
    asm volatile("" ::: "memory");
}

#define MFMA16(A, B, C) __builtin_amdgcn_mfma_f32_16x16x32_f16((A), (B), (C), 0, 0, 0)

__global__ __launch_bounds__(256, 1)
void gru_fused_kernel(const float* __restrict__ X,     // [T,B,64]
                      const float* __restrict__ W_ih,  // [192,64]
                      const float* __restrict__ W_hh,  // [192,64]
                      const float* __restrict__ b_ih,  // [192]
                      const float* __restrict__ b_hh,  // [192]
                      float* __restrict__ out)         // [T*B*64] ++ [B*64]
{
    const int tid   = threadIdx.x;
    const int wq    = tid >> 6;       // unit group
    const int l     = tid & 63;
    const int c     = l & 15;         // batch row within tile / B-col
    const int g4    = l >> 4;         // lane group
    const int u     = wq * 16 + c;    // hidden-unit column
    const int brow0 = blockIdx.x * 16;

    __shared__ __align__(16) _Float16 hbuf[2][16][72];

    const float sRZ = -LOG2E;
    const float sN  = 2.0f * LOG2E;

    // ---- 12 W B-fragments, fp16, pre-scaled, loaded once (48 VGPR) ----
    const half8 Brx0 = loadw8s(W_ih + (u)       * 64 +      8 * g4, sRZ);
    const half8 Brx1 = loadw8s(W_ih + (u)       * 64 + 32 + 8 * g4, sRZ);
    const half8 Bzx0 = loadw8s(W_ih + (64 + u)  * 64 +      8 * g4, sRZ);
    const half8 Bzx1 = loadw8s(W_ih + (64 + u)  * 64 + 32 + 8 * g4, sRZ);
    const half8 Bnx0 = loadw8s(W_ih + (128 + u) * 64 +      8 * g4, sN);
    const half8 Bnx1 = loadw8s(W_ih + (128 + u) * 64 + 32 + 8 * g4, sN);
    const half8 Brh0 = loadw8s(W_hh + (u)       * 64 +      8 * g4, sRZ);
    const half8 Brh1 = loadw8s(W_hh + (u)       * 64 + 32 + 8 * g4, sRZ);
    const half8 Bzh0 = loadw8s(W_hh + (64 + u)  * 64 +      8 * g4, sRZ);
    const half8 Bzh1 = loadw8s(W_hh + (64 + u)  * 64 + 32 + 8 * g4, sRZ);
    const half8 Bnh0 = loadw8s(W_hh + (128 + u) * 64 +      8 * g4, sN);
    const half8 Bnh1 = loadw8s(W_hh + (128 + u) * 64 + 32 + 8 * g4, sN);

    const float rb  = sRZ * (b_ih[u]      + b_hh[u]);
    const float zb  = sRZ * (b_ih[64 + u] + b_hh[64 + u]);
    const float nxb = sN * b_ih[128 + u];
    const float nhb = sN * b_hh[128 + u];

#define ISSUE_X(XB, T) do {                                                   \
        const float* px_ = X + ((size_t)(T) * BATCH + brow0 + c) * 64 + 8 * g4; \
        (XB).a0 = ((const float4*)px_)[0];                                    \
        (XB).a1 = ((const float4*)px_)[1];                                    \
        (XB).b0 = ((const float4*)(px_ + 32))[0];                             \
        (XB).b1 = ((const float4*)(px_ + 32))[1];                             \
    } while (0)

    XBuf xb0, xb1;
    ISSUE_X(xb0, 0);
    ISSUE_X(xb1, 1);

    // zero h(0) buffers
    for (int k = tid; k < 2 * 16 * 72; k += 256)
        ((_Float16*)hbuf)[k] = (_Float16)0.f;
    __syncthreads();

    f32x4 hp = {0.f, 0.f, 0.f, 0.f};

#define STEP(T, XA) do {                                                      \
        const int p_ = (T) & 1;                                               \
        /* issue h reads FIRST: latency covered by x-work below */            \
        const half8 hf0 = *(const half8*)&hbuf[p_][c][8 * g4];                \
        const half8 hf1 = *(const half8*)&hbuf[p_][c][32 + 8 * g4];           \
        /* x fragment (loaded 2 steps ago, in regs) + refill prefetch */      \
        const half8 xf0 = cvt8p((XA).a0, (XA).a1);                            \
        const half8 xf1 = cvt8p((XA).b0, (XA).b1);                            \
        { int tn_ = (T) + 2; if (tn_ > T_STEPS - 1) tn_ = T_STEPS - 1;        \
          ISSUE_X(XA, tn_); }                                                 \
        f32x4 cr  = {rb, rb, rb, rb};                                         \
        f32x4 cz  = {zb, zb, zb, zb};                                         \
        f32x4 cnx = {nxb, nxb, nxb, nxb};                                     \
        f32x4 cnh = {nhb, nhb, nhb, nhb};                                     \
        /* x-MFMAs: independent of h, execute inside the ds_read window */    \
        cr  = MFMA16(xf0, Brx0, cr);  cr  = MFMA16(xf1, Brx1, cr);            \
        cz  = MFMA16(xf0, Bzx0, cz);  cz  = MFMA16(xf1, Bzx1, cz);            \
        cnx = MFMA16(xf0, Bnx0, cnx); cnx = MFMA16(xf1, Bnx1, cnx);           \
        /* h-MFMAs (compiler places the lgkmcnt wait right before these) */   \
        cr  = MFMA16(hf0, Brh0, cr);  cr  = MFMA16(hf1, Brh1, cr);            \
        cz  = MFMA16(hf0, Bzh0, cz);  cz  = MFMA16(hf1, Bzh1, cz);            \
        cnh = MFMA16(hf0, Bnh0, cnh); cnh = MFMA16(hf1, Bnh1, cnh);           \
        _Pragma("unroll")                                                     \
        for (int i = 0; i < 4; ++i) {                                         \
            const float rv = __builtin_amdgcn_rcpf(1.f + exp2f(cr[i]));       \
            const float zv = __builtin_amdgcn_rcpf(1.f + exp2f(cz[i]));       \
            const float npre = fmaf(rv, cnh[i], cnx[i]);                      \
            const float e  = exp2f(npre);                                     \
            const float nv = 1.f - 2.f * __builtin_amdgcn_rcpf(e + 1.f);      \
            const float hn = fmaf(zv, hp[i] - nv, nv);                        \
            hp[i] = hn;                                                       \
            hbuf[p_ ^ 1][4 * g4 + i][u] = (_Float16)hn;                       \
            out[((size_t)(T) * BATCH + brow0 + 4 * g4 + i) * 64 + u] = hn;    \
        }                                                                     \
        block_sync();                                                         \
    } while (0)

    #pragma unroll 1
    for (int t = 0; t < T_STEPS; t += 2) {
        STEP(t,     xb0);
        STEP(t + 1, xb1);
    }

    #pragma unroll
    for (int i = 0; i < 4; ++i)
        out[(size_t)T_STEPS * BATCH * 64 + (brow0 + 4 * g4 + i) * 64 + u] = hp[i];

#undef STEP
#undef ISSUE_X
}

extern "C" void kernel_launch(void* const* d_in, const int* in_sizes, int n_in,
                              void* d_out, int out_size, void* d_ws, size_t ws_size,
                              hipStream_t stream) {
    const float* X    = (const float*)d_in[0];
    const float* W_ih = (const float*)d_in[1];
    const float* W_hh = (const float*)d_in[2];
    const float* b_ih = (const float*)d_in[3];
    const float* b_hh = (const float*)d_in[4];
    float* out = (float*)d_out;

    gru_fused_kernel<<<dim3(BATCH / 16), dim3(256), 0, stream>>>(
        X, W_ih, W_hh, b_ih, b_hh, out);
}